// Round 5
// baseline (166.397 us; speedup 1.0000x reference)
//
#include <hip/hip_runtime.h>

#define MA 64
#define F 128
#define NF 16
#define HID 512
#define LDUB 144    // ub row stride BYTES (128 fp8 + 16 pad)
#define LDT1B 1040  // t1 row stride bytes (512 bf16 + 8 pad elems)
// ub double-buffer base byte offsets (wL buffer eliminated: w lives in regs)
#define UB0 0
#define UB1 9216

typedef float  float4v __attribute__((ext_vector_type(4)));
typedef short  short8  __attribute__((ext_vector_type(8)));
typedef int    int8v   __attribute__((ext_vector_type(8)));

// pack two fp32 -> (bf16(y)<<16)|bf16(x), round-half-up via +0x8000 then v_perm
static __device__ __forceinline__ unsigned int pack2bf(float x, float y) {
    unsigned int a = __float_as_uint(x) + 0x8000u;
    unsigned int b = __float_as_uint(y) + 0x8000u;
    return __builtin_amdgcn_perm(b, a, 0x07060302u);
}
static __device__ __forceinline__ unsigned short f2bf1(float x) {
    return (unsigned short)((__float_as_uint(x) + 0x8000u) >> 16);
}
// pack 4 fp32 -> 4 fp8 e4m3 (RNE, saturating) in one dword
static __device__ __forceinline__ unsigned int pk4fp8(float a, float b, float c, float d) {
    int p = __builtin_amdgcn_cvt_pk_fp8_f32(a, b, 0, false);
    p = __builtin_amdgcn_cvt_pk_fp8_f32(c, d, p, true);
    return (unsigned int)p;
}

// lgkm-only barrier: LDS producer/consumer sync WITHOUT draining vmcnt, so
// global prefetches (afr / aw2) stay in flight across the rendezvous.
#define LGKM_BAR() do {                                        \
    asm volatile("s_waitcnt lgkmcnt(0)" ::: "memory");         \
    __builtin_amdgcn_s_barrier();                              \
    asm volatile("" ::: "memory");                             \
} while (0)

// ---- Pack W1 as fp8 MX A-frags (16x16x128) of W1^T; W2 as bf16 A-frags
// (16x16x32) of W2^T. Direct gather. (unchanged)
__global__ void pack_frags(const float* __restrict__ W1, const float* __restrict__ W2,
                           unsigned char* __restrict__ w1p, unsigned short* __restrict__ w2p) {
    int gid  = blockIdx.x * 4 + (threadIdx.x >> 6);
    int lane = threadIdx.x & 63;
    int arow = lane & 15;
    int kq   = lane >> 4;
    if (gid < 544) {                           // W1: kt (17 over K=2176, 128 each) x jt (32)
        int kt = gid >> 5, jt = gid & 31;
        const float* base = W1 + (size_t)(kt * 128 + kq * 32) * HID + jt * 16 + arow;
        unsigned int o[8];
        #pragma unroll
        for (int p = 0; p < 8; p++)
            o[p] = pk4fp8(base[(p * 4 + 0) * HID], base[(p * 4 + 1) * HID],
                          base[(p * 4 + 2) * HID], base[(p * 4 + 3) * HID]);
        unsigned char* dst = w1p + ((size_t)gid * 64 + lane) * 32;
        *(uint4*)dst        = (uint4){o[0], o[1], o[2], o[3]};
        *(uint4*)(dst + 16) = (uint4){o[4], o[5], o[6], o[7]};
    } else if (gid < 544 + 128) {              // W2: kt (16 over J=512) x mt (8 over 128)
        int g2 = gid - 544;
        int kt = g2 >> 3, mt = g2 & 7;
        const float* base = W2 + (size_t)(kt * 32 + kq * 8) * F + mt * 16 + arow;
        short8 o;
        #pragma unroll
        for (int j = 0; j < 8; j++) o[j] = (short)f2bf1(base[j * F]);
        *(short8*)(w2p + ((size_t)g2 * 64 + lane) * 8) = o;
    }
}

// ---- Main fused kernel: ONE molecule per block, 1024 threads = 16 waves ----
// 4 waves/SIMD. r3 GEMM1 partition (wave owns j-tiles wave*2+{0,1}, all 4
// a-tiles; W1 frags read exactly once per block). NEW vs r3: the Gaussian
// filter w_f is built DIRECTLY in u-GEMM B-fragment registers (each thread
// owns the fixed pair set (a = (wave&3)*16+arow, b = ks2*32+quad*8+j); 16
// masked distances precomputed once, 16 exp+pack per filter). This deletes
// the wL LDS buffer, its 64KB/iter reads + 16KB writes, and removes w from
// the barrier dependency graph -- only the u (ub) round-trip still syncs.
// u-GEMM partition: at = wave&3, c-tiles (wave>>2)*2+{0,1}.
__launch_bounds__(1024, 4)
__global__ void node_conv_mfma(const int* __restrict__ z, const float* __restrict__ rr,
        const float* __restrict__ h, const float* __restrict__ dist,
        const float* __restrict__ wid, const float* __restrict__ b1,
        const float* __restrict__ b2,
        const unsigned char* __restrict__ w1p, const unsigned short* __restrict__ w2p,
        float* __restrict__ out) {
    const int n = blockIdx.x;                  // molecule index
    const int tid = threadIdx.x;
    const int lane = tid & 63;
    const int wave = tid >> 6;                 // 0..15
    const int arow = lane & 15;
    const int quad = lane >> 4;
    const int kgrp = quad * 8;
    const int whi = wave >> 1;                 // GEMM2: c-tile
    const int wlo = wave & 1;                  // GEMM2: a-pair selector
    const int uat  = wave & 3;                 // u-GEMM: a-tile
    const int uct0 = (wave >> 2) * 2;          // u-GEMM: first of 2 c-tiles

    __shared__ __attribute__((aligned(16))) unsigned char lds[66560];
    __shared__ float r_lds[MA][5];             // xyz + mask, stride-5

    const int N = gridDim.x;
    const float* hg = h + (size_t)n * MA * F;

    // ---- z / r passthrough + r/mask staging ----
    if (tid < MA) {
        int zi = z[n * MA + tid];
        out[(size_t)n * MA + tid] = (float)zi;
        r_lds[tid][0] = rr[(n * MA + tid) * 3 + 0];
        r_lds[tid][1] = rr[(n * MA + tid) * 3 + 1];
        r_lds[tid][2] = rr[(n * MA + tid) * 3 + 2];
        r_lds[tid][3] = (zi > -1) ? 1.0f : 0.0f;
    }
    if (tid < MA * 3)
        out[(size_t)N * MA + (size_t)n * MA * 3 + tid] = rr[(size_t)n * MA * 3 + tid];

    // ---- stage h -> ub0 (row-major fp8) ----
    for (int i = tid; i < MA * F / 4; i += 1024) {
        float4 v = ((const float4*)hg)[i];
        int a = i >> 5, c4 = (i & 31) * 4;
        *(unsigned int*)&lds[UB0 + a * LDUB + c4] = pk4fp8(v.x, v.y, v.z, v.w);
    }
    // ---- hT A-fragments in registers (bf16) for u-GEMM: lane holds h[b][c],
    // c = (uct0+cc)*16 + arow, b = ks2*32 + kgrp + j ----
    short8 ah2[2][2];
    #pragma unroll
    for (int cc = 0; cc < 2; cc++) {
        int c = (uct0 + cc) * 16 + arow;
        #pragma unroll
        for (int ks2 = 0; ks2 < 2; ks2++)
            #pragma unroll
            for (int j = 0; j < 8; j++)
                ah2[cc][ks2][j] = (short)f2bf1(hg[(size_t)(ks2 * 32 + kgrp + j) * F + c]);
    }
    // ---- initial A-frag pair (seg 0, j-tiles wave*2+{0,1}) ----
    int8v afr[2];
    {
        const unsigned char* p0 = w1p + ((size_t)((wave * 2) * 64 + lane)) * 32;
        afr[0] = *(const int8v*)p0;
        afr[1] = *(const int8v*)(p0 + 2048);
    }
    __syncthreads();                           // r_lds + ub0 visible (full drain, once)

    // ---- per-thread masked distances for this thread's fixed B-frag pair set:
    // a-atom = uat*16 + arow, b-atom = (i>>3)*32 + kgrp + (i&7), i = 0..15 ----
    float dpre16[16];
    {
        const int athis = uat * 16 + arow;
        float ax = r_lds[athis][0], ay = r_lds[athis][1], az = r_lds[athis][2];
        float am = r_lds[athis][3];
        #pragma unroll
        for (int i = 0; i < 16; i++) {
            int bb = (i >> 3) * 32 + kgrp + (i & 7);
            float dx = ax - r_lds[bb][0];
            float dy = ay - r_lds[bb][1];
            float dz = az - r_lds[bb][2];
            float d = sqrtf(dx * dx + dy * dy + dz * dz + 1e-12f);
            float mm = am * r_lds[bb][3];
            dpre16[i] = d + (1.0f - mm) * 1e4f;   // exp underflows to 0 when masked
        }
    }

    const float4v zf = {0.f, 0.f, 0.f, 0.f};
    float4v acc[2][4];                         // [mt = j-tile][at = a-tile] = 32 AGPRs
    #pragma unroll
    for (int i = 0; i < 2; i++)
        #pragma unroll
        for (int jv = 0; jv < 4; jv++) acc[i][jv] = zf;

    // ---- main loop: 17 K-segments of 128, ONE lgkm barrier per iteration.
    // Interval f: GEMM1 seg f (reads ub[f&1]) -> afr(f+1) prefetch (rides
    // across barrier on vmcnt) -> exp w_f in regs -> u-GEMM -> pack ->
    // write u_f -> ub[(f+1)&1] -> barrier.
    for (int f = 0; f <= NF; f++) {
        const int sel = f & 1;
        const int ubR = sel ? UB1 : UB0;
        const int ubW = sel ? UB0 : UB1;

        // GEMM1 seg f: j-tiles wave*2+{0,1} x 4 a-tiles (E8M0 scale 127 = 1.0)
        #pragma unroll
        for (int at = 0; at < 4; at++) {
            int8v bfr = *(const int8v*)&lds[ubR + (at * 16 + arow) * LDUB + quad * 32];
            acc[0][at] = __builtin_amdgcn_mfma_scale_f32_16x16x128_f8f6f4(
                afr[0], bfr, acc[0][at], 0, 0, 0, 127, 0, 127);
            acc[1][at] = __builtin_amdgcn_mfma_scale_f32_16x16x128_f8f6f4(
                afr[1], bfr, acc[1][at], 0, 0, 0, 127, 0, 127);
        }

        if (f < NF) {
            // prefetch next segment's A-frag pair (WAR on afr: reads issued)
            const unsigned char* pN = w1p + ((size_t)(((f + 1) * 32 + wave * 2) * 64 + lane)) * 32;
            afr[0] = *(const int8v*)pN;
            afr[1] = *(const int8v*)(pN + 2048);

            // exp w_f straight into B-fragment registers (no LDS, no barrier dep)
            float mu = dist[f];
            float isg = 1.0f / wid[f];
            short8 bwf[2];
            #pragma unroll
            for (int ks2 = 0; ks2 < 2; ks2++)
                #pragma unroll
                for (int p = 0; p < 4; p++) {
                    float t0 = dpre16[ks2 * 8 + 2 * p + 0] - mu;
                    float t1 = dpre16[ks2 * 8 + 2 * p + 1] - mu;
                    float e0 = 5.0f * __expf(-t0 * t0 * isg);
                    float e1 = 5.0f * __expf(-t1 * t1 * isg);
                    ((unsigned int*)&bwf[ks2])[p] = pack2bf(e0, e1);
                }

            // u-GEMM: u_f[a][c] = sum_b w_f[a][b] h[b][c]; this wave: a-tile
            // uat, c-tiles uct0+{0,1}. D: lane holds rows c = ct*16+quad*4+r,
            // col a = uat*16+arow -> one 4B fp8 store per cc.
            #pragma unroll
            for (int cc = 0; cc < 2; cc++) {
                float4v ud = zf;
                ud = __builtin_amdgcn_mfma_f32_16x16x32_bf16(ah2[cc][0], bwf[0], ud, 0, 0, 0);
                ud = __builtin_amdgcn_mfma_f32_16x16x32_bf16(ah2[cc][1], bwf[1], ud, 0, 0, 0);
                unsigned int up = pk4fp8(ud[0], ud[1], ud[2], ud[3]);
                *(unsigned int*)&lds[ubW + (uat * 16 + arow) * LDUB + (uct0 + cc) * 16 + quad * 4] = up;
            }
        }
        LGKM_BAR();                            // u_f visible / final: ub reads drained
    }

    // ---- GEMM2 (bf16): out = h + 0.1*mask*(silu(t1) @ W2 + b2) ----
    // Full t1 (64 x 512) staged once (overlays ub). W2 A-frags streamed
    // 2-deep from L2-resident w2p.
    float4 b1v[2];
    #pragma unroll
    for (int mt = 0; mt < 2; mt++)
        b1v[mt] = *(const float4*)&b1[wave * 32 + mt * 16 + quad * 4];

    #pragma unroll
    for (int mt = 0; mt < 2; mt++) {
        #pragma unroll
        for (int at = 0; at < 4; at++) {
            float xs[4];
            #pragma unroll
            for (int r = 0; r < 4; r++) {
                float x = acc[mt][at][r] + ((const float*)&b1v[mt])[r];
                xs[r] = x / (1.0f + __expf(-x));
            }
            uint2 pv = { pack2bf(xs[0], xs[1]), pack2bf(xs[2], xs[3]) };
            *(uint2*)&lds[(at * 16 + arow) * LDT1B + (wave * 32 + mt * 16 + quad * 4) * 2] = pv;
        }
    }
    LGKM_BAR();                                // full t1 visible; aw2 stream rides through

    float4v g2[2] = { zf, zf };                // this wave: c-tile whi, a-pair wlo

    short8 awA = *(const short8*)(w2p + ((size_t)(whi) * 64 + lane) * 8);   // ks=0
    #pragma unroll
    for (int ks2 = 0; ks2 < 8; ks2++) {
        const int k1 = 2 * ks2 + 1;
        short8 awB = *(const short8*)(w2p + ((size_t)(k1 * 8 + whi) * 64 + lane) * 8);
        #pragma unroll
        for (int j = 0; j < 2; j++) {
            short8 bt = *(const short8*)&lds[((wlo * 2 + j) * 16 + arow) * LDT1B + ((2 * ks2) * 32 + kgrp) * 2];
            g2[j] = __builtin_amdgcn_mfma_f32_16x16x32_bf16(awA, bt, g2[j], 0, 0, 0);
        }
        const int k2 = (ks2 < 7) ? 2 * ks2 + 2 : 0;   // harmless re-read on last iter
        awA = *(const short8*)(w2p + ((size_t)(k2 * 8 + whi) * 64 + lane) * 8);
        #pragma unroll
        for (int j = 0; j < 2; j++) {
            short8 bt = *(const short8*)&lds[((wlo * 2 + j) * 16 + arow) * LDT1B + ((2 * ks2 + 1) * 32 + kgrp) * 2];
            g2[j] = __builtin_amdgcn_mfma_f32_16x16x32_bf16(awB, bt, g2[j], 0, 0, 0);
        }
    }

    // D[m=c][n=a]: a = (wlo*2+j)*16+arow, c = whi*16 + quad*4 + r
    float* outh = out + (size_t)N * MA * 4 + (size_t)n * MA * F;
    const int c0 = whi * 16 + quad * 4;
    float4 b2v = *(const float4*)&b2[c0];
    #pragma unroll
    for (int j = 0; j < 2; j++) {
        int a = (wlo * 2 + j) * 16 + arow;
        float m = r_lds[a][3] * 0.1f;
        float4 hv = *(const float4*)&hg[a * F + c0];
        float4 res;
        res.x = hv.x + (g2[j][0] + b2v.x) * m;
        res.y = hv.y + (g2[j][1] + b2v.y) * m;
        res.z = hv.z + (g2[j][2] + b2v.z) * m;
        res.w = hv.w + (g2[j][3] + b2v.w) * m;
        *(float4*)&outh[(size_t)a * F + c0] = res;
    }
}

extern "C" void kernel_launch(void* const* d_in, const int* in_sizes, int n_in,
                              void* d_out, int out_size, void* d_ws, size_t ws_size,
                              hipStream_t stream) {
    const int*   z    = (const int*)d_in[0];
    const float* rr   = (const float*)d_in[1];
    const float* h    = (const float*)d_in[2];
    const float* dist = (const float*)d_in[3];
    const float* wid  = (const float*)d_in[4];
    const float* W1   = (const float*)d_in[5];
    const float* b1   = (const float*)d_in[6];
    const float* W2   = (const float*)d_in[7];
    const float* b2   = (const float*)d_in[8];
    float* out = (float*)d_out;

    int Nmol = in_sizes[0] / MA;                           // 512 molecules

    unsigned char*  w1p = (unsigned char*)d_ws;            // 544*64*32 = 1,114,112 B
    unsigned short* w2p = (unsigned short*)(w1p + (size_t)544 * 64 * 32);  // 128 KB bf16

    pack_frags<<<168, 256, 0, stream>>>(W1, W2, w1p, w2p);
    node_conv_mfma<<<Nmol, 1024, 0, stream>>>(z, rr, h, dist, wid, b1, b2, w1p, w2p, out);
}

// Round 6
// 143.461 us; speedup vs baseline: 1.1599x; 1.1599x over previous
//
#include <hip/hip_runtime.h>

#define MA 64
#define F 128
#define NF 16
#define HID 512
#define LDUB 144    // ub row stride BYTES (128 fp8 + 16 pad)
#define LDWB 144    // wL row stride bytes (64 bf16 + 8 pad elems)
#define LDT1B 1040  // t1 row stride bytes (512 bf16 + 8 pad elems)
// double-buffer base offsets (bytes)
#define UB0 0
#define UB1 9216
#define WL0 18432
#define WL1 27648

typedef float  float4v __attribute__((ext_vector_type(4)));
typedef short  short8  __attribute__((ext_vector_type(8)));
typedef int    int8v   __attribute__((ext_vector_type(8)));

// pack two fp32 -> (bf16(y)<<16)|bf16(x), round-half-up via +0x8000 then v_perm
static __device__ __forceinline__ unsigned int pack2bf(float x, float y) {
    unsigned int a = __float_as_uint(x) + 0x8000u;
    unsigned int b = __float_as_uint(y) + 0x8000u;
    return __builtin_amdgcn_perm(b, a, 0x07060302u);
}
static __device__ __forceinline__ unsigned short f2bf1(float x) {
    return (unsigned short)((__float_as_uint(x) + 0x8000u) >> 16);
}
// pack 4 fp32 -> 4 fp8 e4m3 (RNE, saturating) in one dword
static __device__ __forceinline__ unsigned int pk4fp8(float a, float b, float c, float d) {
    int p = __builtin_amdgcn_cvt_pk_fp8_f32(a, b, 0, false);
    p = __builtin_amdgcn_cvt_pk_fp8_f32(c, d, p, true);
    return (unsigned int)p;
}

// lgkm-only barrier: LDS producer/consumer sync WITHOUT draining vmcnt, so
// global prefetches (afr / aw2) stay in flight across the rendezvous.
#define LGKM_BAR() do {                                        \
    asm volatile("s_waitcnt lgkmcnt(0)" ::: "memory");         \
    __builtin_amdgcn_s_barrier();                              \
    asm volatile("" ::: "memory");                             \
} while (0)

// ---- Pack W1 as fp8 MX A-frags (16x16x128) of W1^T; W2 as bf16 A-frags
// (16x16x32) of W2^T. Direct gather. (unchanged)
__global__ void pack_frags(const float* __restrict__ W1, const float* __restrict__ W2,
                           unsigned char* __restrict__ w1p, unsigned short* __restrict__ w2p) {
    int gid  = blockIdx.x * 4 + (threadIdx.x >> 6);
    int lane = threadIdx.x & 63;
    int arow = lane & 15;
    int kq   = lane >> 4;
    if (gid < 544) {                           // W1: kt (17 over K=2176, 128 each) x jt (32)
        int kt = gid >> 5, jt = gid & 31;
        const float* base = W1 + (size_t)(kt * 128 + kq * 32) * HID + jt * 16 + arow;
        unsigned int o[8];
        #pragma unroll
        for (int p = 0; p < 8; p++)
            o[p] = pk4fp8(base[(p * 4 + 0) * HID], base[(p * 4 + 1) * HID],
                          base[(p * 4 + 2) * HID], base[(p * 4 + 3) * HID]);
        unsigned char* dst = w1p + ((size_t)gid * 64 + lane) * 32;
        *(uint4*)dst        = (uint4){o[0], o[1], o[2], o[3]};
        *(uint4*)(dst + 16) = (uint4){o[4], o[5], o[6], o[7]};
    } else if (gid < 544 + 128) {              // W2: kt (16 over J=512) x mt (8 over 128)
        int g2 = gid - 544;
        int kt = g2 >> 3, mt = g2 & 7;
        const float* base = W2 + (size_t)(kt * 32 + kq * 8) * F + mt * 16 + arow;
        short8 o;
        #pragma unroll
        for (int j = 0; j < 8; j++) o[j] = (short)f2bf1(base[j * F]);
        *(short8*)(w2p + ((size_t)g2 * 64 + lane) * 8) = o;
    }
}

// ---- Main fused kernel: ONE molecule per block, 1024 threads = 16 waves ----
// r3 structure (best: 70us) + WAVE-GROUP PHASE STAGGER: half the waves run
// [GEMM1 -> u-GEMM/exp], half run [u-GEMM/exp -> GEMM1] per interval (both
// orders are dependency-legal with the ub/wL double buffers). Selector is
// (wave>>2)&1 so each SIMD hosts 2 waves of each order -> at any instant the
// LDS pipe (ub/wL reads, ~2.2K cy/iter) and the MFMA pipe (~1.4K cy/iter)
// are BOTH occupied instead of the barrier-lockstep flood that serialized
// them. GEMM1 partition: wave owns j-tiles wave*2+{0,1} x all 4 a-tiles
// (W1 frags read exactly once per block -> minimal L2 traffic).
__launch_bounds__(1024, 4)
__global__ void node_conv_mfma(const int* __restrict__ z, const float* __restrict__ rr,
        const float* __restrict__ h, const float* __restrict__ dist,
        const float* __restrict__ wid, const float* __restrict__ b1,
        const float* __restrict__ b2,
        const unsigned char* __restrict__ w1p, const unsigned short* __restrict__ w2p,
        float* __restrict__ out) {
    const int n = blockIdx.x;                  // molecule index
    const int tid = threadIdx.x;
    const int lane = tid & 63;
    const int wave = tid >> 6;                 // 0..15
    const int arow = lane & 15;
    const int quad = lane >> 4;
    const int kgrp = quad * 8;
    const int whi = wave >> 1;                 // u-GEMM/GEMM2: c-slice
    const int wlo = wave & 1;                  // u-GEMM/GEMM2: a-pair selector
    const bool mfirst = ((wave >> 2) & 1) == 0;  // MFMA-first vs LDS-first order

    __shared__ __attribute__((aligned(16))) unsigned char lds[66560];
    __shared__ float r_lds[MA][5];             // xyz + mask, stride-5

    const int N = gridDim.x;
    const float* hg = h + (size_t)n * MA * F;

    // ---- z / r passthrough + r/mask staging ----
    if (tid < MA) {
        int zi = z[n * MA + tid];
        out[(size_t)n * MA + tid] = (float)zi;
        r_lds[tid][0] = rr[(n * MA + tid) * 3 + 0];
        r_lds[tid][1] = rr[(n * MA + tid) * 3 + 1];
        r_lds[tid][2] = rr[(n * MA + tid) * 3 + 2];
        r_lds[tid][3] = (zi > -1) ? 1.0f : 0.0f;
    }
    if (tid < MA * 3)
        out[(size_t)N * MA + (size_t)n * MA * 3 + tid] = rr[(size_t)n * MA * 3 + tid];

    // ---- stage h -> ub0 (row-major fp8) ----
    for (int i = tid; i < MA * F / 4; i += 1024) {
        float4 v = ((const float4*)hg)[i];
        int a = i >> 5, c4 = (i & 31) * 4;
        *(unsigned int*)&lds[UB0 + a * LDUB + c4] = pk4fp8(v.x, v.y, v.z, v.w);
    }
    // ---- hT A-fragments in registers (bf16): lane holds h[b][c], c = whi*16+arow ----
    short8 ah[2];
    {
        int c = whi * 16 + arow;
        #pragma unroll
        for (int ks2 = 0; ks2 < 2; ks2++)
            #pragma unroll
            for (int j = 0; j < 8; j++)
                ah[ks2][j] = (short)f2bf1(hg[(size_t)(ks2 * 32 + kgrp + j) * F + c]);
    }
    __syncthreads();                           // r_lds + ub0 staged h visible (full drain, once)

    // ---- per-thread pairwise distances (4 pairs/thread), mask folded in ----
    const int wa = tid >> 4;                   // 0..63
    const int wb0 = (tid & 15) * 4;            // 0,4,..,60
    float dpre[4];
    {
        float ax = r_lds[wa][0], ay = r_lds[wa][1], az = r_lds[wa][2];
        float am = r_lds[wa][3];
        #pragma unroll
        for (int j = 0; j < 4; j++) {
            float dx = ax - r_lds[wb0 + j][0];
            float dy = ay - r_lds[wb0 + j][1];
            float dz = az - r_lds[wb0 + j][2];
            float d = sqrtf(dx * dx + dy * dy + dz * dz + 1e-12f);
            float mm = am * r_lds[wb0 + j][3];
            dpre[j] = d + (1.0f - mm) * 1e4f;
        }
    }

    // ---- prime: w filter 0 -> wL0 (bf16), A-frag pair (seg 0) ----
    {
        float mu = dist[0];
        float isg = 1.0f / wid[0];
        float e[4];
        #pragma unroll
        for (int j = 0; j < 4; j++) {
            float t = dpre[j] - mu;
            e[j] = 5.0f * __expf(-t * t * isg);
        }
        uint2 wp = { pack2bf(e[0], e[1]), pack2bf(e[2], e[3]) };
        *(uint2*)&lds[WL0 + wa * LDWB + wb0 * 2] = wp;
    }
    int8v afr[2];                              // this wave's 2 MX A-frags (16 regs)
    {
        const unsigned char* p0 = w1p + ((size_t)((wave * 2) * 64 + lane)) * 32;
        afr[0] = *(const int8v*)p0;
        afr[1] = *(const int8v*)(p0 + 2048);
    }
    LGKM_BAR();                                // w0 + ub0 visible; afr loads ride through

    const float4v zf = {0.f, 0.f, 0.f, 0.f};
    float4v acc[2][4];                         // [mt = j-tile][at = a-tile] = 32 AGPRs
    #pragma unroll
    for (int i = 0; i < 2; i++)
        #pragma unroll
        for (int jv = 0; jv < 4; jv++) acc[i][jv] = zf;

    // ---- phase bodies ----
    auto GEMM1 = [&](int ubR) {
        // all 4 B-frags issued first (pipelined lgkm waits), then 8 MX MFMA
        int8v bfr0 = *(const int8v*)&lds[ubR + (0 * 16 + arow) * LDUB + quad * 32];
        int8v bfr1 = *(const int8v*)&lds[ubR + (1 * 16 + arow) * LDUB + quad * 32];
        int8v bfr2 = *(const int8v*)&lds[ubR + (2 * 16 + arow) * LDUB + quad * 32];
        int8v bfr3 = *(const int8v*)&lds[ubR + (3 * 16 + arow) * LDUB + quad * 32];
        acc[0][0] = __builtin_amdgcn_mfma_scale_f32_16x16x128_f8f6f4(afr[0], bfr0, acc[0][0], 0, 0, 0, 127, 0, 127);
        acc[1][0] = __builtin_amdgcn_mfma_scale_f32_16x16x128_f8f6f4(afr[1], bfr0, acc[1][0], 0, 0, 0, 127, 0, 127);
        acc[0][1] = __builtin_amdgcn_mfma_scale_f32_16x16x128_f8f6f4(afr[0], bfr1, acc[0][1], 0, 0, 0, 127, 0, 127);
        acc[1][1] = __builtin_amdgcn_mfma_scale_f32_16x16x128_f8f6f4(afr[1], bfr1, acc[1][1], 0, 0, 0, 127, 0, 127);
        acc[0][2] = __builtin_amdgcn_mfma_scale_f32_16x16x128_f8f6f4(afr[0], bfr2, acc[0][2], 0, 0, 0, 127, 0, 127);
        acc[1][2] = __builtin_amdgcn_mfma_scale_f32_16x16x128_f8f6f4(afr[1], bfr2, acc[1][2], 0, 0, 0, 127, 0, 127);
        acc[0][3] = __builtin_amdgcn_mfma_scale_f32_16x16x128_f8f6f4(afr[0], bfr3, acc[0][3], 0, 0, 0, 127, 0, 127);
        acc[1][3] = __builtin_amdgcn_mfma_scale_f32_16x16x128_f8f6f4(afr[1], bfr3, acc[1][3], 0, 0, 0, 127, 0, 127);
    };
    auto PREFETCH = [&](int f) {               // afr <- segment f+1 (rides vmcnt across barrier)
        const unsigned char* pN = w1p + ((size_t)(((f + 1) * 32 + wave * 2) * 64 + lane)) * 32;
        afr[0] = *(const int8v*)pN;
        afr[1] = *(const int8v*)(pN + 2048);
    };
    auto UGEMM = [&](int wlR, int ubW) {       // u_f^T = hT @ w_f; write fp8 u to ubW
        float4v ud0 = zf, ud1 = zf;
        #pragma unroll
        for (int ks2 = 0; ks2 < 2; ks2++) {
            short8 bw0 = *(const short8*)&lds[wlR + ((wlo * 2 + 0) * 16 + arow) * LDWB + (ks2 * 32 + kgrp) * 2];
            ud0 = __builtin_amdgcn_mfma_f32_16x16x32_bf16(ah[ks2], bw0, ud0, 0, 0, 0);
            short8 bw1 = *(const short8*)&lds[wlR + ((wlo * 2 + 1) * 16 + arow) * LDWB + (ks2 * 32 + kgrp) * 2];
            ud1 = __builtin_amdgcn_mfma_f32_16x16x32_bf16(ah[ks2], bw1, ud1, 0, 0, 0);
        }
        unsigned int u0 = pk4fp8(ud0[0], ud0[1], ud0[2], ud0[3]);
        unsigned int u1 = pk4fp8(ud1[0], ud1[1], ud1[2], ud1[3]);
        *(unsigned int*)&lds[ubW + ((wlo * 2 + 0) * 16 + arow) * LDUB + whi * 16 + quad * 4] = u0;
        *(unsigned int*)&lds[ubW + ((wlo * 2 + 1) * 16 + arow) * LDUB + whi * 16 + quad * 4] = u1;
    };
    auto EXPW = [&](int f, int wlW) {          // exp w_{f+1} -> write buffer
        if (f <= NF - 2) {
            float mu = dist[f + 1];
            float isg = 1.0f / wid[f + 1];
            float e[4];
            #pragma unroll
            for (int j = 0; j < 4; j++) {
                float t = dpre[j] - mu;
                e[j] = 5.0f * __expf(-t * t * isg);
            }
            uint2 wp = { pack2bf(e[0], e[1]), pack2bf(e[2], e[3]) };
            *(uint2*)&lds[wlW + wa * LDWB + wb0 * 2] = wp;
        }
    };

    // ---- main loop: 17 K-segments of 128, ONE lgkm barrier per iteration.
    // Staggered phase order per wave-group (both orders dependency-legal).
    for (int f = 0; f <= NF; f++) {
        const int sel = f & 1;
        const int ubR = sel ? UB1 : UB0;
        const int ubW = sel ? UB0 : UB1;
        const int wlR = sel ? WL1 : WL0;
        const int wlW = sel ? WL0 : WL1;

        if (mfirst) {
            GEMM1(ubR);
            if (f < NF) {
                PREFETCH(f);
                UGEMM(wlR, ubW);
                EXPW(f, wlW);
            }
        } else {
            if (f < NF) {
                UGEMM(wlR, ubW);
                EXPW(f, wlW);
            }
            GEMM1(ubR);
            if (f < NF) PREFETCH(f);
        }
        LGKM_BAR();                            // u_f + w_{f+1} visible / final: ub reads drained
    }

    // ---- GEMM2 (bf16): out = h + 0.1*mask*(silu(t1) @ W2 + b2) ----
    // Full t1 (64 x 512) staged once (overlays ub/wL). W2 A-frags streamed
    // 2-deep from L2-resident w2p.
    float4 b1v[2];
    #pragma unroll
    for (int mt = 0; mt < 2; mt++)
        b1v[mt] = *(const float4*)&b1[wave * 32 + mt * 16 + quad * 4];

    #pragma unroll
    for (int mt = 0; mt < 2; mt++) {
        #pragma unroll
        for (int at = 0; at < 4; at++) {
            float xs[4];
            #pragma unroll
            for (int r = 0; r < 4; r++) {
                float x = acc[mt][at][r] + ((const float*)&b1v[mt])[r];
                xs[r] = x / (1.0f + __expf(-x));
            }
            uint2 pv = { pack2bf(xs[0], xs[1]), pack2bf(xs[2], xs[3]) };
            *(uint2*)&lds[(at * 16 + arow) * LDT1B + (wave * 32 + mt * 16 + quad * 4) * 2] = pv;
        }
    }
    LGKM_BAR();                                // full t1 visible; aw2 stream rides through

    float4v g2[2] = { zf, zf };                // this wave: c-tile whi, a-pair wlo

    short8 awA = *(const short8*)(w2p + ((size_t)(whi) * 64 + lane) * 8);   // ks=0
    #pragma unroll
    for (int ks2 = 0; ks2 < 8; ks2++) {
        const int k1 = 2 * ks2 + 1;
        short8 awB = *(const short8*)(w2p + ((size_t)(k1 * 8 + whi) * 64 + lane) * 8);
        #pragma unroll
        for (int j = 0; j < 2; j++) {
            short8 bt = *(const short8*)&lds[((wlo * 2 + j) * 16 + arow) * LDT1B + ((2 * ks2) * 32 + kgrp) * 2];
            g2[j] = __builtin_amdgcn_mfma_f32_16x16x32_bf16(awA, bt, g2[j], 0, 0, 0);
        }
        const int k2 = (ks2 < 7) ? 2 * ks2 + 2 : 0;   // harmless re-read on last iter
        awA = *(const short8*)(w2p + ((size_t)(k2 * 8 + whi) * 64 + lane) * 8);
        #pragma unroll
        for (int j = 0; j < 2; j++) {
            short8 bt = *(const short8*)&lds[((wlo * 2 + j) * 16 + arow) * LDT1B + ((2 * ks2 + 1) * 32 + kgrp) * 2];
            g2[j] = __builtin_amdgcn_mfma_f32_16x16x32_bf16(awB, bt, g2[j], 0, 0, 0);
        }
    }

    // D[m=c][n=a]: a = (wlo*2+j)*16+arow, c = whi*16 + quad*4 + r
    float* outh = out + (size_t)N * MA * 4 + (size_t)n * MA * F;
    const int c0 = whi * 16 + quad * 4;
    float4 b2v = *(const float4*)&b2[c0];
    #pragma unroll
    for (int j = 0; j < 2; j++) {
        int a = (wlo * 2 + j) * 16 + arow;
        float m = r_lds[a][3] * 0.1f;
        float4 hv = *(const float4*)&hg[a * F + c0];
        float4 res;
        res.x = hv.x + (g2[j][0] + b2v.x) * m;
        res.y = hv.y + (g2[j][1] + b2v.y) * m;
        res.z = hv.z + (g2[j][2] + b2v.z) * m;
        res.w = hv.w + (g2[j][3] + b2v.w) * m;
        *(float4*)&outh[(size_t)a * F + c0] = res;
    }
}

extern "C" void kernel_launch(void* const* d_in, const int* in_sizes, int n_in,
                              void* d_out, int out_size, void* d_ws, size_t ws_size,
                              hipStream_t stream) {
    const int*   z    = (const int*)d_in[0];
    const float* rr   = (const float*)d_in[1];
    const float* h    = (const float*)d_in[2];
    const float* dist = (const float*)d_in[3];
    const float* wid  = (const float*)d_in[4];
    const float* W1   = (const float*)d_in[5];
    const float* b1   = (const float*)d_in[6];
    const float* W2   = (const float*)d_in[7];
    const float* b2   = (const float*)d_in[8];
    float* out = (float*)d_out;

    int Nmol = in_sizes[0] / MA;                           // 512 molecules

    unsigned char*  w1p = (unsigned char*)d_ws;            // 544*64*32 = 1,114,112 B
    unsigned short* w2p = (unsigned short*)(w1p + (size_t)544 * 64 * 32);  // 128 KB bf16

    pack_frags<<<168, 256, 0, stream>>>(W1, W2, w1p, w2p);
    node_conv_mfma<<<Nmol, 1024, 0, stream>>>(z, rr, h, dist, wid, b1, b2, w1p, w2p, out);
}